// Round 10
// baseline (435.651 us; speedup 1.0000x reference)
//
#include <hip/hip_runtime.h>
#include <math.h>

#define BATCH 4096
#define NF    2048

typedef signed char    i8;
typedef unsigned int   u32;
typedef __attribute__((ext_vector_type(4))) int   intx4;   // i8 MFMA A/B/C
typedef __attribute__((ext_vector_type(4))) float floatx4;

#define LBW 0.022097086912079612f   // 1/sqrt(2048), exact weight bound
#define QMAX 32512.0f               // 127*256 : 16-bit fixed-point full scale
#define AMAX_H 3.0f                 // hidden-activation clamp (pre-act sigma~0.29)

// ---------------------------------------------------------------------------
// Fused prep: one dispatch quantizes the activations (sigmoid of x) AND all
// 4 layers' weights to split-i8 fixed point  v = (V1*256 + V2) * scale.
// Blocks 0..8191: activations; blocks 8192..24575: weights (4096 per layer).
// ---------------------------------------------------------------------------
__global__ __launch_bounds__(256) void prep_kernel(
    const float* __restrict__ x, const float* __restrict__ cw,
    const float* __restrict__ cb,
    const float* __restrict__ w0, const float* __restrict__ w1,
    const float* __restrict__ w2, const float* __restrict__ w3,
    i8* __restrict__ h1o, i8* __restrict__ h2o,
    i8* __restrict__ q1,  i8* __restrict__ q2)
{
    const int bid = blockIdx.x;
    if (bid < 8192) {
        // ---- activation job: h = sigmoid(x*sum(cw)+cb), amax = 1 ----
        const float s = cw[0] + cw[1] + cw[2] + cw[3];
        const float c = cb[0];
        const int i = bid * 256 + threadIdx.x;          // < 2M
        float4 v = ((const float4*)x)[i];
        float vv[4] = {v.x, v.y, v.z, v.w};
        char4 c1, c2;
        #pragma unroll
        for (int j = 0; j < 4; ++j) {
            float r = 1.0f / (1.0f + expf(-(vv[j] * s + c)));
            int X = (int)(r * QMAX + 0.5f);             // [0, 32512]
            int h1 = (X + 128) >> 8;
            int h2 = X - (h1 << 8);
            ((i8*)&c1)[j] = (i8)h1;
            ((i8*)&c2)[j] = (i8)h2;
        }
        *(char4*)&h1o[(size_t)i * 4] = c1;
        *(char4*)&h2o[(size_t)i * 4] = c2;
    } else {
        // ---- weight job: 4096 blocks per layer ----
        const int b2    = bid - 8192;
        const int layer = b2 >> 12;
        const int i     = (b2 & 4095) * 256 + threadIdx.x;   // < 1M
        const float* w = (layer == 0) ? w0 : (layer == 1) ? w1
                       : (layer == 2) ? w2 : w3;
        const size_t base = (size_t)layer * (size_t)NF * NF;
        float4 v = ((const float4*)w)[i];
        float vv[4] = {v.x, v.y, v.z, v.w};
        char4 c1, c2;
        #pragma unroll
        for (int j = 0; j < 4; ++j) {
            int X = (int)floorf(vv[j] * (QMAX / LBW) + 0.5f);
            X = max(-32512, min(32512, X));
            int h1 = (X + 128) >> 8;
            int h2 = X - (h1 << 8);
            ((i8*)&c1)[j] = (i8)h1;
            ((i8*)&c2)[j] = (i8)h2;
        }
        *(char4*)&q1[base + (size_t)i * 4] = c1;
        *(char4*)&q2[base + (size_t)i * 4] = c2;
    }
}

// ---------------------------------------------------------------------------
// Split-i8 MFMA GEMM (exact i32 accumulation):
//   C = relu(A @ W^T + bias) in split-i8 fixed point,
//   XY = 65536*H1W1 + 256*(H1W2+H2W1) [H2W2 dropped, ~1.6e-5 rms/layer]
//
// v11: the occupancy test (v10's goal) in a SAFE launch shape. All eight
// scheduling variants landed 62+-2 us with exactly 8 waves/CU (2/SIMD,
// barrier-locked), MfmaUtil ~32, VALUBusy ~18, Occupancy ~19.7% -- both
// pipes <=1/3 busy: latency-bound, not pipe-bound (LDS floor ~1550
// cyc/tile, MFMA ~490/SIMD, measured 4650). v10 (1024-thr, 16-wave block)
// killed the container -- unproven launch config. v11 gets 16 waves/CU
// with proven shapes: TWO 512-thread blocks per CU.
//   - 128x128 tile, 8 waves (2Mx4N), per-wave 64x32 (acc 16 intx4 = 64
//     VGPR; a-frags streamed in i-loop; total ~100 < the 128/wave cap
//     enforced by __launch_bounds__(512, 4) = 4 waves/SIMD min).
//   - ring-2 LDS = 2 x 32 KB = 64 KiB/block -> 2 blocks/CU (128 KiB).
//   - per-CU LDS traffic 2x(96KB rd + 32KB wr) per 2 tiles = 128 KB/tile
//     equivalent (vs 176 for the 256x128 shape).
//   - ring-2 forces per-tile vmcnt(0), but stages are issued at TILE START
//     (full-tile cover ~2400 cyc >> 900-cyc HBM miss) and the two blocks'
//     barriers are INDEPENDENT -> the CU's LDS and MFMA windows of the two
//     blocks desynchronize (m114 cross-wave pipe overlap).
// Hazards: stage(t+1) writes buf^1, last read at t-1; those reads complete
// before t-1's barrier (lgkm waits precede dependent MFMAs which precede
// the barrier in program order). Reads of buf at t certified by t-1's end
// vmcnt(0)+barrier. Numerics bit-identical to v1-v10.
// ---------------------------------------------------------------------------
#define BM 128
#define BN 128
#define BK 64

#define BUFSZ  32768          // 8K A1 + 8K A2 + 8K B1 + 8K B2 per buffer
#define SEC_A2 8192
#define SEC_B1 16384
#define SEC_B2 24576

__device__ __forceinline__ void stage16(const void* g, void* l) {
    __builtin_amdgcn_global_load_lds(
        (const __attribute__((address_space(1))) u32*)g,
        (__attribute__((address_space(3))) u32*)l, 16, 0, 0);
}

__global__ __launch_bounds__(512, 4) void gemm_i8_split(
    const i8* __restrict__ A1, const i8* __restrict__ A2,
    const i8* __restrict__ B1, const i8* __restrict__ B2,
    const float* __restrict__ bias,
    i8* __restrict__ C1, i8* __restrict__ C2,
    const float* __restrict__ Wh, const float* __restrict__ bh,
    float* __restrict__ outp,
    float combo, float outscale, int last, int M, int N, int K)
{
    extern __shared__ i8 smem[];   // 2 * BUFSZ = 64 KiB

    const int t    = threadIdx.x;
    const int wv   = t >> 6;        // wave 0..7
    const int ln   = t & 63;
    const int quad = ln >> 4;       // 0..3 : 16-byte k-group
    const int ml   = ln & 15;       // 0..15 : row
    const int wm   = wv >> 2;       // 2x4 wave grid: wm 0..1 (M), wn 0..3 (N)
    const int wn   = wv & 3;
    const int bm   = blockIdx.y * BM;
    const int bn   = blockIdx.x * BN;
    const int lnoff = ln * 16;

    // staging: wave wv stages chunk wv (16 rows) of each of A1/A2/B1/B2
    int rA = (bm + wv * 16 + ml) * K + quad * 16;
    int rB = (bn + wv * 16 + ml) * K + quad * 16;

    intx4 zero = {0, 0, 0, 0};
    intx4 acc11[4][2], accX[4][2];
    #pragma unroll
    for (int i = 0; i < 4; ++i)
        #pragma unroll
        for (int j = 0; j < 2; ++j) { acc11[i][j] = zero; accX[i][j] = zero; }

#define FENCE_ asm volatile("" ::: "memory")
#define LDS_(OFF) (*(const intx4*)&smem[(OFF) + lnoff])

    // ---- prologue: stage tile 0 into buffer 0, drain once ----
    stage16(A1 + rA, smem + wv * 1024);
    stage16(A2 + rA, smem + SEC_A2 + wv * 1024);
    stage16(B1 + rB, smem + SEC_B1 + wv * 1024);
    stage16(B2 + rB, smem + SEC_B2 + wv * 1024);
    rA += BK; rB += BK;
    asm volatile("s_waitcnt vmcnt(0)" ::: "memory");
    __builtin_amdgcn_s_barrier();
    FENCE_;

    int rd = 0;                  // buffer being computed (byte offset)

    const int NIT = K >> 6;      // K-tiles (K=2048 -> 32; requires >= 2)
    #pragma unroll 1
    for (int kt = 0; kt < NIT; ++kt) {
        const int wr = BUFSZ - rd;
        // ---- issue stage of tile kt+1 into the other buffer (early) ----
        if (kt < NIT - 1) {
            stage16(A1 + rA, smem + wr + wv * 1024);
            stage16(A2 + rA, smem + wr + SEC_A2 + wv * 1024);
            stage16(B1 + rB, smem + wr + SEC_B1 + wv * 1024);
            stage16(B2 + rB, smem + wr + SEC_B2 + wv * 1024);
            rA += BK; rB += BK;
        }
        FENCE_;
        // ---- fragments + MFMA: compiler-scheduled; a-frags streamed ----
        intx4 b1f0 = LDS_(rd + SEC_B1 + (wn * 2 + 0) * 1024);
        intx4 b1f1 = LDS_(rd + SEC_B1 + (wn * 2 + 1) * 1024);
        intx4 b2f0 = LDS_(rd + SEC_B2 + (wn * 2 + 0) * 1024);
        intx4 b2f1 = LDS_(rd + SEC_B2 + (wn * 2 + 1) * 1024);
        #pragma unroll
        for (int i = 0; i < 4; ++i) {
            intx4 a1 = LDS_(rd + (wm * 4 + i) * 1024);
            intx4 a2 = LDS_(rd + SEC_A2 + (wm * 4 + i) * 1024);
            acc11[i][0] = __builtin_amdgcn_mfma_i32_16x16x64_i8(a1, b1f0, acc11[i][0], 0, 0, 0);
            accX [i][0] = __builtin_amdgcn_mfma_i32_16x16x64_i8(a1, b2f0, accX [i][0], 0, 0, 0);
            accX [i][0] = __builtin_amdgcn_mfma_i32_16x16x64_i8(a2, b1f0, accX [i][0], 0, 0, 0);
            acc11[i][1] = __builtin_amdgcn_mfma_i32_16x16x64_i8(a1, b1f1, acc11[i][1], 0, 0, 0);
            accX [i][1] = __builtin_amdgcn_mfma_i32_16x16x64_i8(a1, b2f1, accX [i][1], 0, 0, 0);
            accX [i][1] = __builtin_amdgcn_mfma_i32_16x16x64_i8(a2, b1f1, accX [i][1], 0, 0, 0);
        }
        // ---- tile boundary: drain stage(t+1) (full tile of cover) ----
        asm volatile("s_waitcnt vmcnt(0)" ::: "memory");
        __builtin_amdgcn_s_barrier();
        FENCE_;
        rd = wr;
    }

#undef LDS_
#undef FENCE_

    if (!last) {
        // ---- epilogue: dequant + bias + relu + requant; n=ml, m=quad*4+r
        #pragma unroll
        for (int j = 0; j < 2; ++j) {
            const int n  = bn + wn * 32 + j * 16 + ml;
            const float bv = bias[n];
            #pragma unroll
            for (int i = 0; i < 4; ++i) {
                #pragma unroll
                for (int r = 0; r < 4; ++r) {
                    const int m = bm + wm * 64 + i * 16 + quad * 4 + r;
                    float v = fmaf(65536.0f, (float)acc11[i][j][r],
                                   256.0f * (float)accX[i][j][r]) * combo + bv;
                    v = fmaxf(v, 0.0f);
                    int X = (int)(fminf(v * outscale, QMAX) + 0.5f);
                    int h1 = (X + 128) >> 8;
                    int h2 = X - (h1 << 8);
                    C1[(size_t)m * N + n] = (i8)h1;
                    C2[(size_t)m * N + n] = (i8)h2;
                }
            }
        }
    } else {
        // ---- fused head: out[m,c] = sum_n relu(..)*Wh[c][n] + bh[c] ----
        float wh0[2], wh1[2], bv[2];
        #pragma unroll
        for (int j = 0; j < 2; ++j) {
            const int n = bn + wn * 32 + j * 16 + ml;
            bv[j]  = bias[n];
            wh0[j] = Wh[n];
            wh1[j] = Wh[NF + n];
        }
        #pragma unroll
        for (int i = 0; i < 4; ++i) {
            #pragma unroll
            for (int r = 0; r < 4; ++r) {
                float s0 = 0.0f, s1 = 0.0f;
                #pragma unroll
                for (int j = 0; j < 2; ++j) {
                    float v = fmaf(65536.0f, (float)acc11[i][j][r],
                                   256.0f * (float)accX[i][j][r]) * combo + bv[j];
                    v = fmaxf(v, 0.0f);
                    s0 = fmaf(v, wh0[j], s0);
                    s1 = fmaf(v, wh1[j], s1);
                }
                #pragma unroll
                for (int off = 8; off > 0; off >>= 1) {
                    s0 += __shfl_xor(s0, off, 64);
                    s1 += __shfl_xor(s1, off, 64);
                }
                if (ml == 0) {
                    const int m = bm + wm * 64 + i * 16 + quad * 4 + r;
                    if (bn == 0 && wn == 0) { s0 += bh[0]; s1 += bh[1]; }
                    atomicAdd(&outp[(size_t)m * 2 + 0], s0);
                    atomicAdd(&outp[(size_t)m * 2 + 1], s1);
                }
            }
        }
    }
}

// ===========================================================================
// fp32 fallback path — used only if ws_size < 64 MB
// ===========================================================================
__global__ __launch_bounds__(256) void act_kernel_f32(
    const float* __restrict__ x, const float* __restrict__ conv_w,
    const float* __restrict__ conv_b, float* __restrict__ h, int n4)
{
    const float s = conv_w[0] + conv_w[1] + conv_w[2] + conv_w[3];
    const float c = conv_b[0];
    int i = blockIdx.x * blockDim.x + threadIdx.x;
    if (i < n4) {
        float4 v = ((const float4*)x)[i];
        float4 r;
        r.x = 1.0f / (1.0f + expf(-(v.x * s + c)));
        r.y = 1.0f / (1.0f + expf(-(v.y * s + c)));
        r.z = 1.0f / (1.0f + expf(-(v.z * s + c)));
        r.w = 1.0f / (1.0f + expf(-(v.w * s + c)));
        ((float4*)h)[i] = r;
    }
}

#define FBM 128
#define FBN 128
#define FBK 16
#define FPAD 4

__global__ __launch_bounds__(256) void gemm_bias_relu_f32(
    const float* __restrict__ A, const float* __restrict__ W,
    const float* __restrict__ bias, float* __restrict__ C,
    int M, int N, int K, int do_relu)
{
    __shared__ float As[FBK][FBM + FPAD];
    __shared__ float Bs[FBK][FBN + FPAD];
    const int t  = threadIdx.x;
    const int bm = blockIdx.y * FBM;
    const int bn = blockIdx.x * FBN;
    const int tn = (t & 15) * 8;
    const int tm = (t >> 4) * 8;
    const int r0 = t >> 2;
    const int kv = (t & 3) << 2;
    float acc[8][8] = {};
    for (int k0 = 0; k0 < K; k0 += FBK) {
        #pragma unroll
        for (int half = 0; half < 2; ++half) {
            const int row = r0 + half * 64;
            float4 av = *(const float4*)&A[(size_t)(bm + row) * K + k0 + kv];
            As[kv + 0][row] = av.x; As[kv + 1][row] = av.y;
            As[kv + 2][row] = av.z; As[kv + 3][row] = av.w;
            float4 bv = *(const float4*)&W[(size_t)(bn + row) * K + k0 + kv];
            Bs[kv + 0][row] = bv.x; Bs[kv + 1][row] = bv.y;
            Bs[kv + 2][row] = bv.z; Bs[kv + 3][row] = bv.w;
        }
        __syncthreads();
        #pragma unroll
        for (int kk = 0; kk < FBK; ++kk) {
            float a[8], b[8];
            *(float4*)&a[0] = *(const float4*)&As[kk][tm];
            *(float4*)&a[4] = *(const float4*)&As[kk][tm + 4];
            *(float4*)&b[0] = *(const float4*)&Bs[kk][tn];
            *(float4*)&b[4] = *(const float4*)&Bs[kk][tn + 4];
            #pragma unroll
            for (int i = 0; i < 8; ++i)
                #pragma unroll
                for (int j = 0; j < 8; ++j)
                    acc[i][j] = fmaf(a[i], b[j], acc[i][j]);
        }
        __syncthreads();
    }
    #pragma unroll
    for (int i = 0; i < 8; ++i) {
        const int row = bm + tm + i;
        #pragma unroll
        for (int j = 0; j < 8; j += 4) {
            float4 v;
            v.x = acc[i][j + 0] + bias[bn + tn + j + 0];
            v.y = acc[i][j + 1] + bias[bn + tn + j + 1];
            v.z = acc[i][j + 2] + bias[bn + tn + j + 2];
            v.w = acc[i][j + 3] + bias[bn + tn + j + 3];
            if (do_relu) {
                v.x = fmaxf(v.x, 0.0f); v.y = fmaxf(v.y, 0.0f);
                v.z = fmaxf(v.z, 0.0f); v.w = fmaxf(v.w, 0.0f);
            }
            *(float4*)&C[(size_t)row * N + bn + tn + j] = v;
        }
    }
}

__global__ __launch_bounds__(256) void head_kernel_f32(
    const float* __restrict__ h, const float* __restrict__ Wh,
    const float* __restrict__ bh, float* __restrict__ out)
{
    const int wave = threadIdx.x >> 6;
    const int lane = threadIdx.x & 63;
    const int row  = blockIdx.x * 4 + wave;
    const float* hr = h + (size_t)row * NF;
    float acc0 = 0.0f, acc1 = 0.0f;
    for (int k = lane * 4; k < NF; k += 256) {
        float4 v  = *(const float4*)&hr[k];
        float4 w0 = *(const float4*)&Wh[k];
        float4 w1 = *(const float4*)&Wh[NF + k];
        acc0 += v.x * w0.x + v.y * w0.y + v.z * w0.z + v.w * w0.w;
        acc1 += v.x * w1.x + v.y * w1.y + v.z * w1.z + v.w * w1.w;
    }
    #pragma unroll
    for (int off = 32; off > 0; off >>= 1) {
        acc0 += __shfl_down(acc0, off, 64);
        acc1 += __shfl_down(acc1, off, 64);
    }
    if (lane == 0) {
        out[row * 2 + 0] = acc0 + bh[0];
        out[row * 2 + 1] = acc1 + bh[1];
    }
}

// ---------------------------------------------------------------------------
extern "C" void kernel_launch(void* const* d_in, const int* in_sizes, int n_in,
                              void* d_out, int out_size, void* d_ws, size_t ws_size,
                              hipStream_t stream)
{
    const float* x      = (const float*)d_in[0];
    const float* conv_w = (const float*)d_in[1];
    const float* conv_b = (const float*)d_in[2];
    const float* Ws[4]  = {(const float*)d_in[3], (const float*)d_in[5],
                           (const float*)d_in[7], (const float*)d_in[9]};
    const float* bs[4]  = {(const float*)d_in[4], (const float*)d_in[6],
                           (const float*)d_in[8], (const float*)d_in[10]};
    const float* Wh     = (const float*)d_in[11];
    const float* bh     = (const float*)d_in[12];
    float* out = (float*)d_out;

    const size_t AE = (size_t)BATCH * NF;      // 8 MB activation array (i8)
    const size_t WE = (size_t)NF * NF;         // 4 MB weight array (i8)
    const size_t need_i8 = 4 * AE + 8 * WE;    // 64 MB

    const int n4 = (BATCH * NF) / 4;

    if (ws_size >= need_i8) {
        // 64 KiB dynamic LDS (standard envelope; opt-in call kept for safety)
        static int attr_done = 0;
        if (!attr_done) {
            (void)hipFuncSetAttribute(
                reinterpret_cast<const void*>(gemm_i8_split),
                hipFuncAttributeMaxDynamicSharedMemorySize, 2 * BUFSZ);
            attr_done = 1;
        }

        i8* base = (i8*)d_ws;
        i8* a01 = base;                 // ping H1
        i8* a02 = a01 + AE;             // ping H2
        i8* a11 = a02 + AE;             // pong H1
        i8* a12 = a11 + AE;             // pong H2
        i8* wq1 = a12 + AE;             // 4 layers W1
        i8* wq2 = wq1 + 4 * WE;         // 4 layers W2

        // zero out for the fused-head atomics (graph-capturable)
        hipMemsetAsync(out, 0, (size_t)out_size * sizeof(float), stream);

        prep_kernel<<<8192 + 16384, 256, 0, stream>>>(
            x, conv_w, conv_b, Ws[0], Ws[1], Ws[2], Ws[3],
            a01, a02, wq1, wq2);

        const float sW = LBW / QMAX;
        const float outscale = QMAX / AMAX_H;
        dim3 grid(NF / BN, BATCH / BM);   // (16, 32) = 512 blocks = 2/CU

        i8 *in1 = a01, *in2 = a02, *o1 = a11, *o2 = a12;
        for (int l = 0; l < 4; ++l) {
            const float sA = ((l == 0) ? 1.0f : AMAX_H) / QMAX;
            gemm_i8_split<<<grid, 512, 2 * BUFSZ, stream>>>(
                in1, in2, wq1 + (size_t)l * WE, wq2 + (size_t)l * WE,
                bs[l], o1, o2, Wh, bh, out,
                sA * sW, outscale, (l == 3) ? 1 : 0, BATCH, NF, NF);
            i8* t1 = in1; i8* t2 = in2;
            in1 = o1; in2 = o2; o1 = t1; o2 = t2;
        }
    } else {
        float* ws0 = (float*)d_ws;
        float* ws1 = ws0 + AE;
        act_kernel_f32<<<(n4 + 255) / 256, 256, 0, stream>>>(x, conv_w, conv_b, ws0, n4);
        dim3 fgrid(NF / FBN, BATCH / FBM);
        gemm_bias_relu_f32<<<fgrid, 256, 0, stream>>>(ws0, Ws[0], bs[0], ws1, BATCH, NF, NF, 1);
        gemm_bias_relu_f32<<<fgrid, 256, 0, stream>>>(ws1, Ws[1], bs[1], ws0, BATCH, NF, NF, 1);
        gemm_bias_relu_f32<<<fgrid, 256, 0, stream>>>(ws0, Ws[2], bs[2], ws1, BATCH, NF, NF, 1);
        gemm_bias_relu_f32<<<fgrid, 256, 0, stream>>>(ws1, Ws[3], bs[3], ws0, BATCH, NF, NF, 1);
        head_kernel_f32<<<BATCH / 4, 256, 0, stream>>>(ws0, Wh, bh, out);
    }
}

// Round 11
// 388.026 us; speedup vs baseline: 1.1227x; 1.1227x over previous
//
#include <hip/hip_runtime.h>
#include <math.h>

#define BATCH 4096
#define NF    2048

typedef signed char    i8;
typedef unsigned int   u32;
typedef __attribute__((ext_vector_type(4))) int   intx4;   // i8 MFMA A/B/C
typedef __attribute__((ext_vector_type(4))) float floatx4;

#define LBW 0.022097086912079612f   // 1/sqrt(2048), exact weight bound
#define QMAX 32512.0f               // 127*256 : 16-bit fixed-point full scale
#define AMAX_H 3.0f                 // hidden-activation clamp (pre-act sigma~0.29)

// ---------------------------------------------------------------------------
// Fused prep: one dispatch quantizes the activations (sigmoid of x) AND all
// 4 layers' weights to split-i8 fixed point  v = (V1*256 + V2) * scale.
// Blocks 0..8191: activations; blocks 8192..24575: weights (4096 per layer).
// ---------------------------------------------------------------------------
__global__ __launch_bounds__(256) void prep_kernel(
    const float* __restrict__ x, const float* __restrict__ cw,
    const float* __restrict__ cb,
    const float* __restrict__ w0, const float* __restrict__ w1,
    const float* __restrict__ w2, const float* __restrict__ w3,
    i8* __restrict__ h1o, i8* __restrict__ h2o,
    i8* __restrict__ q1,  i8* __restrict__ q2)
{
    const int bid = blockIdx.x;
    if (bid < 8192) {
        // ---- activation job: h = sigmoid(x*sum(cw)+cb), amax = 1 ----
        const float s = cw[0] + cw[1] + cw[2] + cw[3];
        const float c = cb[0];
        const int i = bid * 256 + threadIdx.x;          // < 2M
        float4 v = ((const float4*)x)[i];
        float vv[4] = {v.x, v.y, v.z, v.w};
        char4 c1, c2;
        #pragma unroll
        for (int j = 0; j < 4; ++j) {
            float r = 1.0f / (1.0f + expf(-(vv[j] * s + c)));
            int X = (int)(r * QMAX + 0.5f);             // [0, 32512]
            int h1 = (X + 128) >> 8;
            int h2 = X - (h1 << 8);
            ((i8*)&c1)[j] = (i8)h1;
            ((i8*)&c2)[j] = (i8)h2;
        }
        *(char4*)&h1o[(size_t)i * 4] = c1;
        *(char4*)&h2o[(size_t)i * 4] = c2;
    } else {
        // ---- weight job: 4096 blocks per layer ----
        const int b2    = bid - 8192;
        const int layer = b2 >> 12;
        const int i     = (b2 & 4095) * 256 + threadIdx.x;   // < 1M
        const float* w = (layer == 0) ? w0 : (layer == 1) ? w1
                       : (layer == 2) ? w2 : w3;
        const size_t base = (size_t)layer * (size_t)NF * NF;
        float4 v = ((const float4*)w)[i];
        float vv[4] = {v.x, v.y, v.z, v.w};
        char4 c1, c2;
        #pragma unroll
        for (int j = 0; j < 4; ++j) {
            int X = (int)floorf(vv[j] * (QMAX / LBW) + 0.5f);
            X = max(-32512, min(32512, X));
            int h1 = (X + 128) >> 8;
            int h2 = X - (h1 << 8);
            ((i8*)&c1)[j] = (i8)h1;
            ((i8*)&c2)[j] = (i8)h2;
        }
        *(char4*)&q1[base + (size_t)i * 4] = c1;
        *(char4*)&q2[base + (size_t)i * 4] = c2;
    }
}

// ---------------------------------------------------------------------------
// Split-i8 MFMA GEMM (exact i32 accumulation):
//   C = relu(A @ W^T + bias) in split-i8 fixed point,
//   XY = 65536*H1W1 + 256*(H1W2+H2W1) [H2W2 dropped, ~1.6e-5 rms/layer]
//
// v12 = v8 (best GEMM, 61.7us: cross-tile fragment prefetch, A ring-3 +
// B ring-3, counted vmcnt(4), 144 KiB) + two untested mechanisms:
//  1. XCD-aware BIJECTIVE block swizzle (T1): FETCH=69.7MB vs 24MB unique
//     (~3x L2-fill over-fetch). 1D grid of 256; each of the 8 XCDs owns a
//     4(bm)x8(bn) chunk (A 4MB + B 4MB = 8MB footprint vs scattered 24MB).
//     nwg=256 % 8 == 0 -> simple bijective form valid (m204).
//  2. Independent accX split: v8's MFMA3 triple had accX accumulated
//     TWICE SERIALLY per (i,j) -> 16 dependent MFMA pairs per wave per
//     tile on the matrix pipe's dep latency. accXa (a1*b2) and accXb
//     (a2*b1) are now separate accumulators, i32-summed in the epilogue
//     (exact; bit-identical output). All 48 MFMAs/tile independent.
//     VGPR ~120 -> ~184 < 256 at 2 waves/SIMD (launch_bounds(512,2)).
// Wait schedule, rings, hazards: identical to v8 (verified tile-by-tile).
// Numerics bit-identical to v1-v11. Requires NIT >= 4 (K=2048 -> 32).
// ---------------------------------------------------------------------------
#define BM 256
#define BN 128
#define BK 64

#define ASLOT  32768          // 16K A1 + 16K A2 per A ring slot (x3)
#define ASEC2  16384
#define BBASE  98304          // B ring-3 starts after 3 A slots
#define BSLOT  16384          // 8K B1 + 8K B2 per B ring slot (x3)
#define BSEC2  8192
#define LDS_TOTAL 147456      // 144 KiB (proven envelope)

__device__ __forceinline__ void stage16(const void* g, void* l) {
    __builtin_amdgcn_global_load_lds(
        (const __attribute__((address_space(1))) u32*)g,
        (__attribute__((address_space(3))) u32*)l, 16, 0, 0);
}

__global__ __launch_bounds__(512, 2) void gemm_i8_split(
    const i8* __restrict__ A1, const i8* __restrict__ A2,
    const i8* __restrict__ B1, const i8* __restrict__ B2,
    const float* __restrict__ bias,
    i8* __restrict__ C1, i8* __restrict__ C2,
    const float* __restrict__ Wh, const float* __restrict__ bh,
    float* __restrict__ outp,
    float combo, float outscale, int last, int M, int N, int K)
{
    extern __shared__ i8 smem[];   // 144 KiB

    const int t    = threadIdx.x;
    const int wv   = t >> 6;        // wave 0..7
    const int ln   = t & 63;
    const int quad = ln >> 4;       // 0..3 : 16-byte k-group
    const int ml   = ln & 15;       // 0..15 : row
    const int wm   = wv >> 1;       // 4x2 wave grid: wm 0..3 (M), wn 0..1 (N)
    const int wn   = wv & 1;

    // ---- XCD-aware bijective swizzle: 256 blocks, 8 XCDs, 4bm x 8bn chunks
    // (grid is 16 bm-blocks x 16 bn-blocks; valid because 256 % 8 == 0)
    const int bid  = blockIdx.x;
    const int xcd  = bid & 7;
    const int idx  = bid >> 3;            // 0..31 within XCD
    const int bm   = (((xcd >> 1) << 2) + (idx >> 3)) * BM;  // 4 chunk-rows
    const int bn   = (((xcd & 1) << 3) + (idx & 7)) * BN;    // 2 chunk-cols
    const int lnoff = ln * 16;

    // staging offsets: wave wv stages A-chunks {2wv,2wv+1}, B-chunk wv
    int rA0 = (bm + (wv * 2 + 0) * 16 + ml) * K + quad * 16;
    int rA1 = (bm + (wv * 2 + 1) * 16 + ml) * K + quad * 16;
    int rBs = (bn +  wv * 16          + ml) * K + quad * 16;

    intx4 zero = {0, 0, 0, 0};
    intx4 acc11[4][4], accXa[4][4], accXb[4][4];
    #pragma unroll
    for (int i = 0; i < 4; ++i)
        #pragma unroll
        for (int j = 0; j < 4; ++j) {
            acc11[i][j] = zero; accXa[i][j] = zero; accXb[i][j] = zero;
        }

    intx4 b1f[4], b2f[4];                        // current tile's B frags
    intx4 a1f0, a1f1, a1f2, a1f3;                // A frags, streamed in-place
    intx4 a2f0, a2f1, a2f2, a2f3;

#define FENCE_ asm volatile("" ::: "memory")

    // ---- prologue: issue B(0),B(1),A(0),A(1); vmcnt(4) leaves A(1) ----
    stage16(B1 + rBs, smem + BBASE + 0 * BSLOT + wv * 1024);
    stage16(B2 + rBs, smem + BBASE + 0 * BSLOT + BSEC2 + wv * 1024);
    rBs += BK; FENCE_;
    stage16(B1 + rBs, smem + BBASE + 1 * BSLOT + wv * 1024);
    stage16(B2 + rBs, smem + BBASE + 1 * BSLOT + BSEC2 + wv * 1024);
    rBs += BK; FENCE_;
    stage16(A1 + rA0, smem + (wv * 2 + 0) * 1024);
    stage16(A1 + rA1, smem + (wv * 2 + 1) * 1024);
    stage16(A2 + rA0, smem + ASEC2 + (wv * 2 + 0) * 1024);
    stage16(A2 + rA1, smem + ASEC2 + (wv * 2 + 1) * 1024);
    rA0 += BK; rA1 += BK; FENCE_;
    stage16(A1 + rA0, smem + ASLOT + (wv * 2 + 0) * 1024);
    stage16(A1 + rA1, smem + ASLOT + (wv * 2 + 1) * 1024);
    stage16(A2 + rA0, smem + ASLOT + ASEC2 + (wv * 2 + 0) * 1024);
    stage16(A2 + rA1, smem + ASLOT + ASEC2 + (wv * 2 + 1) * 1024);
    rA0 += BK; rA1 += BK;
    asm volatile("s_waitcnt vmcnt(4)" ::: "memory");   // B0,B1,A0 resident
    __builtin_amdgcn_s_barrier();
    FENCE_;
    // B frags for tile 0 (slot 0)
    #pragma unroll
    for (int j = 0; j < 4; ++j) {
        b1f[j] = *(const intx4*)&smem[BBASE + (wn * 4 + j) * 1024 + lnoff];
        b2f[j] = *(const intx4*)&smem[BBASE + BSEC2 + (wn * 4 + j) * 1024 + lnoff];
    }

    int aoff = 0;              // A read slot (tile u):        slot u%3
    int awr  = 2 * ASLOT;      // A write slot (tile u+2):     slot (u+2)%3
    int bnx  = 1 * BSLOT;      // B early-read slot (tile u+1): slot (u+1)%3
    int bwr  = 2 * BSLOT;      // B write slot (tile u+2):     slot (u+2)%3

#define ARD1(i) (*(const intx4*)&smem[aoff + ((wm * 4 + (i)) * 1024) + lnoff])
#define ARD2(i) (*(const intx4*)&smem[aoff + ASEC2 + ((wm * 4 + (i)) * 1024) + lnoff])
#define MFMA12(i, A1R, A2R) \
    _Pragma("unroll") \
    for (int j = 0; j < 4; ++j) { \
        acc11[i][j] = __builtin_amdgcn_mfma_i32_16x16x64_i8(A1R, b1f[j], acc11[i][j], 0, 0, 0); \
        accXa[i][j] = __builtin_amdgcn_mfma_i32_16x16x64_i8(A1R, b2f[j], accXa[i][j], 0, 0, 0); \
        accXb[i][j] = __builtin_amdgcn_mfma_i32_16x16x64_i8(A2R, b1f[j], accXb[i][j], 0, 0, 0); \
    }

// One K-tile. SG: stage B(u+2)+A(u+2); ERB: early-read B(u+1) frags;
// WAITOP: counted tile-end vmcnt (literal asm).
#define KTILE(SG, ERB, WAITOP) { \
    a1f0 = ARD1(0); a2f0 = ARD2(0); \
    if (SG) { \
        stage16(B1 + rBs, smem + BBASE + bwr + wv * 1024); \
        stage16(B2 + rBs, smem + BBASE + bwr + BSEC2 + wv * 1024); \
        rBs += BK; \
    } \
    FENCE_; \
    if (SG) { \
        stage16(A1 + rA0, smem + awr + (wv * 2 + 0) * 1024); \
        stage16(A1 + rA1, smem + awr + (wv * 2 + 1) * 1024); \
        stage16(A2 + rA0, smem + awr + ASEC2 + (wv * 2 + 0) * 1024); \
        stage16(A2 + rA1, smem + awr + ASEC2 + (wv * 2 + 1) * 1024); \
        rA0 += BK; rA1 += BK; \
    } \
    FENCE_; \
    a1f1 = ARD1(1); a2f1 = ARD2(1); \
    MFMA12(0, a1f0, a2f0); \
    a1f2 = ARD1(2); a2f2 = ARD2(2); \
    MFMA12(1, a1f1, a2f1); \
    a1f3 = ARD1(3); a2f3 = ARD2(3); \
    MFMA12(2, a1f2, a2f2); \
    MFMA12(3, a1f3, a2f3); \
    if (ERB) { \
        _Pragma("unroll") \
        for (int j = 0; j < 4; ++j) { \
            b1f[j] = *(const intx4*)&smem[BBASE + bnx + (wn * 4 + j) * 1024 + lnoff]; \
            b2f[j] = *(const intx4*)&smem[BBASE + bnx + BSEC2 + (wn * 4 + j) * 1024 + lnoff]; \
        } \
    } \
    WAITOP; \
    __builtin_amdgcn_s_barrier(); \
    FENCE_; \
    aoff = (aoff == 2 * ASLOT) ? 0 : aoff + ASLOT; \
    awr  = (awr  == 2 * ASLOT) ? 0 : awr  + ASLOT; \
    bnx  = (bnx  == 2 * BSLOT) ? 0 : bnx  + BSLOT; \
    bwr  = (bwr  == 2 * BSLOT) ? 0 : bwr  + BSLOT; \
}

    const int NIT = K >> 6;          // K-tiles (requires >= 4; K=2048 -> 32)
    #pragma unroll 1
    for (int kt = 0; kt < NIT - 2; ++kt) {
        KTILE(1, 1, asm volatile("s_waitcnt vmcnt(4)" ::: "memory"))
    }
    KTILE(0, 1, asm volatile("s_waitcnt vmcnt(0)" ::: "memory"))
    KTILE(0, 0, asm volatile("s_waitcnt vmcnt(0)" ::: "memory"))

#undef KTILE
#undef MFMA12
#undef ARD1
#undef ARD2
#undef FENCE_

    if (!last) {
        // ---- epilogue: dequant + bias + relu + requant; n=ml, m=quad*4+r
        #pragma unroll
        for (int j = 0; j < 4; ++j) {
            const int n  = bn + wn * 64 + j * 16 + ml;
            const float bv = bias[n];
            #pragma unroll
            for (int i = 0; i < 4; ++i) {
                #pragma unroll
                for (int r = 0; r < 4; ++r) {
                    const int m = bm + wm * 64 + i * 16 + quad * 4 + r;
                    const int xsum = accXa[i][j][r] + accXb[i][j][r]; // exact
                    float v = fmaf(65536.0f, (float)acc11[i][j][r],
                                   256.0f * (float)xsum) * combo + bv;
                    v = fmaxf(v, 0.0f);
                    int X = (int)(fminf(v * outscale, QMAX) + 0.5f);
                    int h1 = (X + 128) >> 8;
                    int h2 = X - (h1 << 8);
                    C1[(size_t)m * N + n] = (i8)h1;
                    C2[(size_t)m * N + n] = (i8)h2;
                }
            }
        }
    } else {
        // ---- fused head: out[m,c] = sum_n relu(..)*Wh[c][n] + bh[c] ----
        float wh0[4], wh1[4], bv[4];
        #pragma unroll
        for (int j = 0; j < 4; ++j) {
            const int n = bn + wn * 64 + j * 16 + ml;
            bv[j]  = bias[n];
            wh0[j] = Wh[n];
            wh1[j] = Wh[NF + n];
        }
        #pragma unroll
        for (int i = 0; i < 4; ++i) {
            #pragma unroll
            for (int r = 0; r < 4; ++r) {
                float s0 = 0.0f, s1 = 0.0f;
                #pragma unroll
                for (int j = 0; j < 4; ++j) {
                    const int xsum = accXa[i][j][r] + accXb[i][j][r]; // exact
                    float v = fmaf(65536.0f, (float)acc11[i][j][r],
                                   256.0f * (float)xsum) * combo + bv[j];
                    v = fmaxf(v, 0.0f);
                    s0 = fmaf(v, wh0[j], s0);
                    s1 = fmaf(v, wh1[j], s1);
                }
                #pragma unroll
                for (int off = 8; off > 0; off >>= 1) {
                    s0 += __shfl_xor(s0, off, 64);
                    s1 += __shfl_xor(s1, off, 64);
                }
                if (ml == 0) {
                    const int m = bm + wm * 64 + i * 16 + quad * 4 + r;
                    if (bn == 0 && wn == 0) { s0 += bh[0]; s1 += bh[1]; }
                    atomicAdd(&outp[(size_t)m * 2 + 0], s0);
                    atomicAdd(&outp[(size_t)m * 2 + 1], s1);
                }
            }
        }
    }
}

// ===========================================================================
// fp32 fallback path — used only if ws_size < 64 MB
// ===========================================================================
__global__ __launch_bounds__(256) void act_kernel_f32(
    const float* __restrict__ x, const float* __restrict__ conv_w,
    const float* __restrict__ conv_b, float* __restrict__ h, int n4)
{
    const float s = conv_w[0] + conv_w[1] + conv_w[2] + conv_w[3];
    const float c = conv_b[0];
    int i = blockIdx.x * blockDim.x + threadIdx.x;
    if (i < n4) {
        float4 v = ((const float4*)x)[i];
        float4 r;
        r.x = 1.0f / (1.0f + expf(-(v.x * s + c)));
        r.y = 1.0f / (1.0f + expf(-(v.y * s + c)));
        r.z = 1.0f / (1.0f + expf(-(v.z * s + c)));
        r.w = 1.0f / (1.0f + expf(-(v.w * s + c)));
        ((float4*)h)[i] = r;
    }
}

#define FBM 128
#define FBN 128
#define FBK 16
#define FPAD 4

__global__ __launch_bounds__(256) void gemm_bias_relu_f32(
    const float* __restrict__ A, const float* __restrict__ W,
    const float* __restrict__ bias, float* __restrict__ C,
    int M, int N, int K, int do_relu)
{
    __shared__ float As[FBK][FBM + FPAD];
    __shared__ float Bs[FBK][FBN + FPAD];
    const int t  = threadIdx.x;
    const int bm = blockIdx.y * FBM;
    const int bn = blockIdx.x * FBN;
    const int tn = (t & 15) * 8;
    const int tm = (t >> 4) * 8;
    const int r0 = t >> 2;
    const int kv = (t & 3) << 2;
    float acc[8][8] = {};
    for (int k0 = 0; k0 < K; k0 += FBK) {
        #pragma unroll
        for (int half = 0; half < 2; ++half) {
            const int row = r0 + half * 64;
            float4 av = *(const float4*)&A[(size_t)(bm + row) * K + k0 + kv];
            As[kv + 0][row] = av.x; As[kv + 1][row] = av.y;
            As[kv + 2][row] = av.z; As[kv + 3][row] = av.w;
            float4 bv = *(const float4*)&W[(size_t)(bn + row) * K + k0 + kv];
            Bs[kv + 0][row] = bv.x; Bs[kv + 1][row] = bv.y;
            Bs[kv + 2][row] = bv.z; Bs[kv + 3][row] = bv.w;
        }
        __syncthreads();
        #pragma unroll
        for (int kk = 0; kk < FBK; ++kk) {
            float a[8], b[8];
            *(float4*)&a[0] = *(const float4*)&As[kk][tm];
            *(float4*)&a[4] = *(const float4*)&As[kk][tm + 4];
            *(float4*)&b[0] = *(const float4*)&Bs[kk][tn];
            *(float4*)&b[4] = *(const float4*)&Bs[kk][tn + 4];
            #pragma unroll
            for (int i = 0; i < 8; ++i)
                #pragma unroll
                for (int j = 0; j < 8; ++j)
                    acc[i][j] = fmaf(a[i], b[j], acc[i][j]);
        }
        __syncthreads();
    }
    #pragma unroll
    for (int i = 0; i < 8; ++i) {
        const int row = bm + tm + i;
        #pragma unroll
        for (int j = 0; j < 8; j += 4) {
            float4 v;
            v.x = acc[i][j + 0] + bias[bn + tn + j + 0];
            v.y = acc[i][j + 1] + bias[bn + tn + j + 1];
            v.z = acc[i][j + 2] + bias[bn + tn + j + 2];
            v.w = acc[i][j + 3] + bias[bn + tn + j + 3];
            if (do_relu) {
                v.x = fmaxf(v.x, 0.0f); v.y = fmaxf(v.y, 0.0f);
                v.z = fmaxf(v.z, 0.0f); v.w = fmaxf(v.w, 0.0f);
            }
            *(float4*)&C[(size_t)row * N + bn + tn + j] = v;
        }
    }
}

__global__ __launch_bounds__(256) void head_kernel_f32(
    const float* __restrict__ h, const float* __restrict__ Wh,
    const float* __restrict__ bh, float* __restrict__ out)
{
    const int wave = threadIdx.x >> 6;
    const int lane = threadIdx.x & 63;
    const int row  = blockIdx.x * 4 + wave;
    const float* hr = h + (size_t)row * NF;
    float acc0 = 0.0f, acc1 = 0.0f;
    for (int k = lane * 4; k < NF; k += 256) {
        float4 v  = *(const float4*)&hr[k];
        float4 w0 = *(const float4*)&Wh[k];
        float4 w1 = *(const float4*)&Wh[NF + k];
        acc0 += v.x * w0.x + v.y * w0.y + v.z * w0.z + v.w * w0.w;
        acc1 += v.x * w1.x + v.y * w1.y + v.z * w1.z + v.w * w1.w;
    }
    #pragma unroll
    for (int off = 32; off > 0; off >>= 1) {
        acc0 += __shfl_down(acc0, off, 64);
        acc1 += __shfl_down(acc1, off, 64);
    }
    if (lane == 0) {
        out[row * 2 + 0] = acc0 + bh[0];
        out[row * 2 + 1] = acc1 + bh[1];
    }
}

// ---------------------------------------------------------------------------
extern "C" void kernel_launch(void* const* d_in, const int* in_sizes, int n_in,
                              void* d_out, int out_size, void* d_ws, size_t ws_size,
                              hipStream_t stream)
{
    const float* x      = (const float*)d_in[0];
    const float* conv_w = (const float*)d_in[1];
    const float* conv_b = (const float*)d_in[2];
    const float* Ws[4]  = {(const float*)d_in[3], (const float*)d_in[5],
                           (const float*)d_in[7], (const float*)d_in[9]};
    const float* bs[4]  = {(const float*)d_in[4], (const float*)d_in[6],
                           (const float*)d_in[8], (const float*)d_in[10]};
    const float* Wh     = (const float*)d_in[11];
    const float* bh     = (const float*)d_in[12];
    float* out = (float*)d_out;

    const size_t AE = (size_t)BATCH * NF;      // 8 MB activation array (i8)
    const size_t WE = (size_t)NF * NF;         // 4 MB weight array (i8)
    const size_t need_i8 = 4 * AE + 8 * WE;    // 64 MB

    const int n4 = (BATCH * NF) / 4;

    if (ws_size >= need_i8) {
        // opt-in to 144 KiB dynamic LDS (once; host-side attribute, not a
        // stream op, safe under graph capture). Proven envelope.
        static int attr_done = 0;
        if (!attr_done) {
            (void)hipFuncSetAttribute(
                reinterpret_cast<const void*>(gemm_i8_split),
                hipFuncAttributeMaxDynamicSharedMemorySize, LDS_TOTAL);
            attr_done = 1;
        }

        i8* base = (i8*)d_ws;
        i8* a01 = base;                 // ping H1
        i8* a02 = a01 + AE;             // ping H2
        i8* a11 = a02 + AE;             // pong H1
        i8* a12 = a11 + AE;             // pong H2
        i8* wq1 = a12 + AE;             // 4 layers W1
        i8* wq2 = wq1 + 4 * WE;         // 4 layers W2

        // zero out for the fused-head atomics (graph-capturable)
        hipMemsetAsync(out, 0, (size_t)out_size * sizeof(float), stream);

        prep_kernel<<<8192 + 16384, 256, 0, stream>>>(
            x, conv_w, conv_b, Ws[0], Ws[1], Ws[2], Ws[3],
            a01, a02, wq1, wq2);

        const float sW = LBW / QMAX;
        const float outscale = QMAX / AMAX_H;
        // 1D grid of 256; kernel derives (bm,bn) via XCD-bijective swizzle
        dim3 grid(256, 1);

        i8 *in1 = a01, *in2 = a02, *o1 = a11, *o2 = a12;
        for (int l = 0; l < 4; ++l) {
            const float sA = ((l == 0) ? 1.0f : AMAX_H) / QMAX;
            gemm_i8_split<<<grid, 512, LDS_TOTAL, stream>>>(
                in1, in2, wq1 + (size_t)l * WE, wq2 + (size_t)l * WE,
                bs[l], o1, o2, Wh, bh, out,
                sA * sW, outscale, (l == 3) ? 1 : 0, BATCH, NF, NF);
            i8* t1 = in1; i8* t2 = in2;
            in1 = o1; in2 = o2; o1 = t1; o2 = t2;
        }
    } else {
        float* ws0 = (float*)d_ws;
        float* ws1 = ws0 + AE;
        act_kernel_f32<<<(n4 + 255) / 256, 256, 0, stream>>>(x, conv_w, conv_b, ws0, n4);
        dim3 fgrid(NF / FBN, BATCH / FBM);
        gemm_bias_relu_f32<<<fgrid, 256, 0, stream>>>(ws0, Ws[0], bs[0], ws1, BATCH, NF, NF, 1);
        gemm_bias_relu_f32<<<fgrid, 256, 0, stream>>>(ws1, Ws[1], bs[1], ws0, BATCH, NF, NF, 1);
        gemm_bias_relu_f32<<<fgrid, 256, 0, stream>>>(ws0, Ws[2], bs[2], ws1, BATCH, NF, NF, 1);
        gemm_bias_relu_f32<<<fgrid, 256, 0, stream>>>(ws1, Ws[3], bs[3], ws0, BATCH, NF, NF, 1);
        head_kernel_f32<<<BATCH / 4, 256, 0, stream>>>(ws0, Wh, bh, out);
    }
}